// Round 26
// baseline (26.607 us; speedup 1.0000x reference)
//
#include <hip/hip_runtime.h>
#include <math.h>

// Problem constants
#define BB 8
#define CC 3
#define DD 24
#define HH 128
#define WW 128
#define HW (HH * WW)
#define OCC 16
#define HOUT 126
#define WOUT 126

typedef short bf16x8 __attribute__((ext_vector_type(8)));   // 4 VGPR
typedef float f32x4 __attribute__((ext_vector_type(4)));
typedef float f4v __attribute__((ext_vector_type(4)));
typedef unsigned int u32;
typedef u32 u32x4 __attribute__((ext_vector_type(4)));

#define MFMA(a, b, c) __builtin_amdgcn_mfma_f32_16x16x32_bf16((a), (b), (c), 0, 0, 0)
// (a>>16) | (c & 0xffff0000) == v_perm_b32(hi=c, lo=a, 0x07060302)
#define PKHI(a, c) __builtin_amdgcn_perm((c), (a), 0x07060302u)

// ROUND 26 = r25 + (a) prefetch distance 3 (triple Raw buffer; the
// pack-then-reload anti-dependency carries over since (dz+2)%3 ==
// (dz+5)%3) + (b) s_setprio(1) around the MFMA cluster (T5: +4-7% for
// independent-wave structures, m191; ours has no barriers). Numerics
// (x trunc-bf16, w RTN-bf16, row-triple bijection, 3 MFMA/step) are
// r25-verbatim -> absmax must stay 3.906e-3.
struct Raw {
  f4v a;   // row 2g, cols q15..q15+3
  f4v b;   // row 2g+1
  u32 c;   // row 8 (g<3) / dummy (g=3)
};

__device__ __forceinline__ f4v ld4(const float* p) {
  f4v v;
  __builtin_memcpy(&v, p, 16);  // align-4 vector load (gfx950 unaligned OK)
  return v;
}

__device__ __forceinline__ void load_raw(const float* __restrict__ xp,
                                         int offA, int offB, int offC,
                                         Raw& r) {
  r.a = ld4(xp + offA);
  r.b = ld4(xp + offB);
  r.c = __float_as_uint(xp[offC]);
}

__device__ __forceinline__ void pack_hi(const Raw& r, bf16x8& fh) {
  u32x4 hd;
  hd[0] = PKHI(__float_as_uint(r.a.x), __float_as_uint(r.a.y));
  hd[1] = PKHI(__float_as_uint(r.a.z), __float_as_uint(r.b.x));
  hd[2] = PKHI(__float_as_uint(r.b.y), __float_as_uint(r.b.z));
  hd[3] = PKHI(r.c, r.c);
  fh = __builtin_bit_cast(bf16x8, hd);
}

// One dz step (distance-3): pack plane dz+2 from ubuf = buf[(dz+2)%3],
// reload the SAME buffer with plane dz+5, 3 MFMAs under setprio, min.
__device__ __forceinline__ void dz_step(const float* __restrict__ xb, int pnext,
                                        int offA, int offB, int offC,
                                        const bf16x8 (&wa)[3], Raw& ubuf,
                                        bf16x8& fa, bf16x8& fb, bf16x8& fc,
                                        const f32x4& z4, f32x4& mn) {
  pack_hi(ubuf, fc);                                          // consume dz+2
  load_raw(xb + (size_t)pnext * HW, offA, offB, offC, ubuf);  // prefetch dz+5
  __builtin_amdgcn_s_setprio(1);
  f32x4 acc = MFMA(wa[0], fa, z4);
  acc = MFMA(wa[1], fb, acc);
  acc = MFMA(wa[2], fc, acc);
  __builtin_amdgcn_s_setprio(0);
  mn.x = fminf(mn.x, acc.x);
  mn.y = fminf(mn.y, acc.y);
  mn.z = fminf(mn.z, acc.z);
  mn.w = fminf(mn.w, acc.w);
}

// Tail variant: no prefetch.
__device__ __forceinline__ void dz_step_nl(const bf16x8 (&wa)[3], Raw& ubuf,
                                           bf16x8& fa, bf16x8& fb, bf16x8& fc,
                                           const f32x4& z4, f32x4& mn) {
  pack_hi(ubuf, fc);
  __builtin_amdgcn_s_setprio(1);
  f32x4 acc = MFMA(wa[0], fa, z4);
  acc = MFMA(wa[1], fb, acc);
  acc = MFMA(wa[2], fc, acc);
  __builtin_amdgcn_s_setprio(0);
  mn.x = fminf(mn.x, acc.x);
  mn.y = fminf(mn.y, acc.y);
  mn.z = fminf(mn.z, acc.z);
  mn.w = fminf(mn.w, acc.w);
}

// 256-thread blocks = 4 independent waves, wave wv handles w-tile
// wti = blockIdx.z*4+wv. Implicit-GEMM per wave: C[oc=16][px=16] via
// mfma_f32_16x16x32_bf16, A = weights (oc x K, single-term RTN-bf16),
// B = im2col (K x px, single-term trunc-bf16). Row-triple bijection
// (r25): g owns rows 2g,2g+1 (j=0-2 row 2g kw=j; j=3-5 row 2g+1; j=6 row8
// kw=g for g<3; j=7 pad) -> 3 VMEM instr/plane. A and B share it, so the
// contraction is a k-order permutation only. C/D: col=lane&15=pixel,
// row=(lane>>4)*4+reg=oc (m89-verified).
__global__ __launch_bounds__(256) void conv_min_softmax_mfma(
    const float* __restrict__ x, const float* __restrict__ wt,
    float* __restrict__ out) {
  const int tid = threadIdx.x;
  const int lane = tid & 63;
  const int wv = tid >> 6;            // wave id 0..3
  const int q15 = lane & 15;          // pixel (B col) and oc (A row)
  const int g = lane >> 4;            // row-pair group
  const int b = blockIdx.x;
  const int h = blockIdx.y;
  const int wti = blockIdx.z * 4 + wv;
  const int w0 = (wti == 7) ? 110 : wti * 16;  // overlap last tile (no OOB)

  // Per-lane plane-relative offsets for the 3 loads.
  const int rA = 2 * g;        // rows 0,2,4,6
  const int rB = 2 * g + 1;    // rows 1,3,5,7
  const int base = w0 + q15;
  const int offA = (rA / 3) * DD * HW + (rA % 3) * WW + base;
  const int offB = (rB / 3) * DD * HW + (rB % 3) * WW + base;
  const int offC = 2 * DD * HW + 2 * WW + base + ((g < 3) ? g : 0);

  // Weight fragments (A), per kd-tile t: single-term RTN bf16, same
  // row-triple bijection; pads (j=7 always; j=6 for g=3) = 0.
  bf16x8 wa[3];
#pragma unroll
  for (int t = 0; t < 3; ++t) {
    u32 u[8];
#pragma unroll
    for (int j = 0; j < 8; ++j) {
      float v = 0.f;
      if (j < 3) {
        v = wt[q15 * 81 + (rA / 3) * 27 + t * 9 + (rA % 3) * 3 + j];
      } else if (j < 6) {
        v = wt[q15 * 81 + (rB / 3) * 27 + t * 9 + (rB % 3) * 3 + (j - 3)];
      } else if (j == 6 && g < 3) {
        v = wt[q15 * 81 + 2 * 27 + t * 9 + 2 * 3 + g];
      }
      const u32 ub = __float_as_uint(v);
      u[j] = ub + 0x7fffu + ((ub >> 16) & 1u);  // round-to-nearest-even bf16
    }
    u32x4 hd;
#pragma unroll
    for (int p = 0; p < 4; ++p) hd[p] = PKHI(u[2 * p], u[2 * p + 1]);
    wa[t] = __builtin_bit_cast(bf16x8, hd);
  }

  const float* xb = x + ((size_t)b * CC * DD) * HW + (size_t)h * WW;

  // Prologue: planes 0,1 packed immediately; planes 2,3,4 raw in B2,B0,B1.
  Raw b0, b1, b2;
  bf16x8 f0, f1, f2;
  load_raw(xb + (size_t)0 * HW, offA, offB, offC, b0);
  load_raw(xb + (size_t)1 * HW, offA, offB, offC, b1);
  pack_hi(b0, f0);
  pack_hi(b1, f1);
  load_raw(xb + (size_t)2 * HW, offA, offB, offC, b2);
  load_raw(xb + (size_t)3 * HW, offA, offB, offC, b0);
  load_raw(xb + (size_t)4 * HW, offA, offB, offC, b1);

  const f32x4 z4 = {0.f, 0.f, 0.f, 0.f};
  f32x4 mn = {INFINITY, INFINITY, INFINITY, INFINITY};

  // Steps dz=0..17: buffer (dz+2)%3 holds plane dz+2; reload with dz+5.
#pragma clang loop unroll(disable)
  for (int dzb = 0; dzb < 18; dzb += 3) {
    dz_step(xb, dzb + 5, offA, offB, offC, wa, b2, f0, f1, f2, z4, mn);
    dz_step(xb, dzb + 6, offA, offB, offC, wa, b0, f1, f2, f0, z4, mn);
    dz_step(xb, dzb + 7, offA, offB, offC, wa, b1, f2, f0, f1, z4, mn);
  }
  // dz=18: pack plane 20 (b2), prefetch plane 23 into b2.
  dz_step(xb, 23, offA, offB, offC, wa, b2, f0, f1, f2, z4, mn);
  // dz=19..21: planes 21 (b0), 22 (b1), 23 (b2); nothing left to prefetch.
  dz_step_nl(wa, b0, f1, f2, f0, z4, mn);
  dz_step_nl(wa, b1, f2, f0, f1, z4, mn);
  dz_step_nl(wa, b2, f0, f1, f2, z4, mn);

  // Softmax over oc for this lane's pixel: 4 in-lane regs (oc = g*4+r) +
  // lanes sharing q15 across g (xor 16, 32).
  float mx = fmaxf(fmaxf(mn.x, mn.y), fmaxf(mn.z, mn.w));
  mx = fmaxf(mx, __shfl_xor(mx, 16));
  mx = fmaxf(mx, __shfl_xor(mx, 32));
  const float e0 = __expf(mn.x - mx);
  const float e1 = __expf(mn.y - mx);
  const float e2 = __expf(mn.z - mx);
  const float e3 = __expf(mn.w - mx);
  float s = (e0 + e1) + (e2 + e3);
  s += __shfl_xor(s, 16);
  s += __shfl_xor(s, 32);
  const float inv = 1.f / s;

  // Store: out[b][oc = g*4+r][h][w0+q15]; 16 consecutive pixels per (g,r).
  float* ob = out + (((size_t)(b * OCC + g * 4) * HOUT + h) * WOUT) + w0 + q15;
  const size_t os = (size_t)HOUT * WOUT;
  ob[0 * os] = e0 * inv;
  ob[1 * os] = e1 * inv;
  ob[2 * os] = e2 * inv;
  ob[3 * os] = e3 * inv;
}

extern "C" void kernel_launch(void* const* d_in, const int* in_sizes, int n_in,
                              void* d_out, int out_size, void* d_ws, size_t ws_size,
                              hipStream_t stream) {
  const float* x = (const float*)d_in[0];
  const float* wt = (const float*)d_in[1];
  float* out = (float*)d_out;

  dim3 grid(BB, HOUT, 2);   // b (XCD-pinned), h, w-tile-pair
  dim3 block(256, 1, 1);    // 4 waves = 4 w-tiles
  conv_min_softmax_mfma<<<grid, block, 0, stream>>>(x, wt, out);
}

// Round 27
// 25.043 us; speedup vs baseline: 1.0624x; 1.0624x over previous
//
#include <hip/hip_runtime.h>
#include <math.h>

// Problem constants
#define BB 8
#define CC 3
#define DD 24
#define HH 128
#define WW 128
#define HW (HH * WW)
#define OCC 16
#define HOUT 126
#define WOUT 126

typedef short bf16x8 __attribute__((ext_vector_type(8)));   // 4 VGPR
typedef float f32x4 __attribute__((ext_vector_type(4)));
typedef float f4v __attribute__((ext_vector_type(4)));
typedef unsigned int u32;
typedef u32 u32x4 __attribute__((ext_vector_type(4)));

#define MFMA(a, b, c) __builtin_amdgcn_mfma_f32_16x16x32_bf16((a), (b), (c), 0, 0, 0)
// (a>>16) | (c & 0xffff0000) == v_perm_b32(hi=c, lo=a, 0x07060302)
#define PKHI(a, c) __builtin_amdgcn_perm((c), (a), 0x07060302u)

// ROUND 27 = ROUND 25 VERBATIM (best verified: 25.1 us, absmax 3.906e-3).
// r26's distance-3 + setprio both-at-once regressed (26.6 us) -> revert per
// pre-commit. Final structure: row-triple k-slot bijection -> 3 VMEM
// instr/plane (1 unaligned dwordx4 per row-pair row + 1 dword row 8);
// group g owns rows 2g,2g+1 (row=(c,kh)=(r/3,r%3)); slots j=0-2 = (row 2g,
// kw=j), j=3-5 = (row 2g+1, kw=j-3), j=6 = (row 8, kw=g) for g<3, j=7 pad.
// Pack = 4 v_perm_b32: d0=pk(a0,a1), d1=pk(a2,b0), d2=pk(b1,b2),
// d3=pk(c,c). Numerics: x trunc-bf16, w RTN-bf16, 3 MFMA/step (absmax
// 2^-8). Distance-2 pack-then-reload register schedule (r19/r20).
struct Raw {
  f4v a;   // row 2g, cols q15..q15+3
  f4v b;   // row 2g+1
  u32 c;   // row 8 (g<3) / dummy (g=3)
};

__device__ __forceinline__ f4v ld4(const float* p) {
  f4v v;
  __builtin_memcpy(&v, p, 16);  // align-4 vector load (gfx950 unaligned OK)
  return v;
}

__device__ __forceinline__ void load_raw(const float* __restrict__ xp,
                                         int offA, int offB, int offC,
                                         Raw& r) {
  r.a = ld4(xp + offA);
  r.b = ld4(xp + offB);
  r.c = __float_as_uint(xp[offC]);
}

__device__ __forceinline__ void pack_hi(const Raw& r, bf16x8& fh) {
  u32x4 hd;
  hd[0] = PKHI(__float_as_uint(r.a.x), __float_as_uint(r.a.y));
  hd[1] = PKHI(__float_as_uint(r.a.z), __float_as_uint(r.b.x));
  hd[2] = PKHI(__float_as_uint(r.b.y), __float_as_uint(r.b.z));
  hd[3] = PKHI(r.c, r.c);
  fh = __builtin_bit_cast(bf16x8, hd);
}

// One dz step (distance-2 schedule): pack plane dz+2 from ubuf, reload the
// SAME buffer with plane dz+4 (anti-dependency keeps order), 3 MFMAs
// (K = 3 planes x 27), running min.
__device__ __forceinline__ void dz_step(const float* __restrict__ xb, int pnext,
                                        int offA, int offB, int offC,
                                        const bf16x8 (&wa)[3], Raw& ubuf,
                                        bf16x8& fa, bf16x8& fb, bf16x8& fc,
                                        const f32x4& z4, f32x4& mn) {
  pack_hi(ubuf, fc);                                     // consume dz+2
  load_raw(xb + (size_t)pnext * HW, offA, offB, offC, ubuf);  // prefetch dz+4
  f32x4 acc = MFMA(wa[0], fa, z4);
  acc = MFMA(wa[1], fb, acc);
  acc = MFMA(wa[2], fc, acc);
  mn.x = fminf(mn.x, acc.x);
  mn.y = fminf(mn.y, acc.y);
  mn.z = fminf(mn.z, acc.z);
  mn.w = fminf(mn.w, acc.w);
}

// Tail variant: no prefetch.
__device__ __forceinline__ void dz_step_nl(const bf16x8 (&wa)[3], Raw& ubuf,
                                           bf16x8& fa, bf16x8& fb, bf16x8& fc,
                                           const f32x4& z4, f32x4& mn) {
  pack_hi(ubuf, fc);
  f32x4 acc = MFMA(wa[0], fa, z4);
  acc = MFMA(wa[1], fb, acc);
  acc = MFMA(wa[2], fc, acc);
  mn.x = fminf(mn.x, acc.x);
  mn.y = fminf(mn.y, acc.y);
  mn.z = fminf(mn.z, acc.z);
  mn.w = fminf(mn.w, acc.w);
}

// 256-thread blocks = 4 independent waves, wave wv handles w-tile
// wti = blockIdx.z*4+wv. Implicit-GEMM per wave: C[oc=16][px=16] via
// mfma_f32_16x16x32_bf16, A = weights (oc x K, single-term RTN-bf16),
// B = im2col (K x px, single-term trunc-bf16). A and B share the row-triple
// bijection above, so the contraction is a k-order permutation only.
// C/D: col=lane&15=pixel, row=(lane>>4)*4+reg=oc (m89-verified).
__global__ __launch_bounds__(256) void conv_min_softmax_mfma(
    const float* __restrict__ x, const float* __restrict__ wt,
    float* __restrict__ out) {
  const int tid = threadIdx.x;
  const int lane = tid & 63;
  const int wv = tid >> 6;            // wave id 0..3
  const int q15 = lane & 15;          // pixel (B col) and oc (A row)
  const int g = lane >> 4;            // row-pair group
  const int b = blockIdx.x;
  const int h = blockIdx.y;
  const int wti = blockIdx.z * 4 + wv;
  const int w0 = (wti == 7) ? 110 : wti * 16;  // overlap last tile (no OOB)

  // Per-lane plane-relative offsets for the 3 loads.
  const int rA = 2 * g;        // rows 0,2,4,6
  const int rB = 2 * g + 1;    // rows 1,3,5,7
  const int base = w0 + q15;
  const int offA = (rA / 3) * DD * HW + (rA % 3) * WW + base;
  const int offB = (rB / 3) * DD * HW + (rB % 3) * WW + base;
  const int offC = 2 * DD * HW + 2 * WW + base + ((g < 3) ? g : 0);

  // Weight fragments (A), per kd-tile t: single-term RTN bf16, same
  // row-triple bijection; pads (j=7 always; j=6 for g=3) = 0.
  bf16x8 wa[3];
#pragma unroll
  for (int t = 0; t < 3; ++t) {
    u32 u[8];
#pragma unroll
    for (int j = 0; j < 8; ++j) {
      float v = 0.f;
      if (j < 3) {
        v = wt[q15 * 81 + (rA / 3) * 27 + t * 9 + (rA % 3) * 3 + j];
      } else if (j < 6) {
        v = wt[q15 * 81 + (rB / 3) * 27 + t * 9 + (rB % 3) * 3 + (j - 3)];
      } else if (j == 6 && g < 3) {
        v = wt[q15 * 81 + 2 * 27 + t * 9 + 2 * 3 + g];
      }
      const u32 ub = __float_as_uint(v);
      u[j] = ub + 0x7fffu + ((ub >> 16) & 1u);  // round-to-nearest-even bf16
    }
    u32x4 hd;
#pragma unroll
    for (int p = 0; p < 4; ++p) hd[p] = PKHI(u[2 * p], u[2 * p + 1]);
    wa[t] = __builtin_bit_cast(bf16x8, hd);
  }

  const float* xb = x + ((size_t)b * CC * DD) * HW + (size_t)h * WW;

  // Prologue: planes 0,1 packed immediately; planes 2,3 raw in U0,U1.
  Raw u0, u1;
  bf16x8 f0, f1, f2;
  load_raw(xb + (size_t)0 * HW, offA, offB, offC, u0);
  load_raw(xb + (size_t)1 * HW, offA, offB, offC, u1);
  pack_hi(u0, f0);
  pack_hi(u1, f1);
  load_raw(xb + (size_t)2 * HW, offA, offB, offC, u0);
  load_raw(xb + (size_t)3 * HW, offA, offB, offC, u1);

  const f32x4 z4 = {0.f, 0.f, 0.f, 0.f};
  f32x4 mn = {INFINITY, INFINITY, INFINITY, INFINITY};

  // dz = 0..17: period-6 (U parity x F rotation); step dz packs plane dz+2
  // and prefetches plane dz+4.
#pragma clang loop unroll(disable)
  for (int dzb = 0; dzb < 18; dzb += 6) {
    dz_step(xb, dzb + 4, offA, offB, offC, wa, u0, f0, f1, f2, z4, mn);
    dz_step(xb, dzb + 5, offA, offB, offC, wa, u1, f1, f2, f0, z4, mn);
    dz_step(xb, dzb + 6, offA, offB, offC, wa, u0, f2, f0, f1, z4, mn);
    dz_step(xb, dzb + 7, offA, offB, offC, wa, u1, f0, f1, f2, z4, mn);
    dz_step(xb, dzb + 8, offA, offB, offC, wa, u0, f1, f2, f0, z4, mn);
    dz_step(xb, dzb + 9, offA, offB, offC, wa, u1, f2, f0, f1, z4, mn);
  }
  // Tail dz = 18..21; last two steps have no remaining planes to prefetch.
  dz_step(xb, 22, offA, offB, offC, wa, u0, f0, f1, f2, z4, mn);
  dz_step(xb, 23, offA, offB, offC, wa, u1, f1, f2, f0, z4, mn);
  dz_step_nl(wa, u0, f2, f0, f1, z4, mn);
  dz_step_nl(wa, u1, f0, f1, f2, z4, mn);

  // Softmax over oc for this lane's pixel: 4 in-lane regs (oc = g*4+r) +
  // lanes sharing q15 across g (xor 16, 32).
  float mx = fmaxf(fmaxf(mn.x, mn.y), fmaxf(mn.z, mn.w));
  mx = fmaxf(mx, __shfl_xor(mx, 16));
  mx = fmaxf(mx, __shfl_xor(mx, 32));
  const float e0 = __expf(mn.x - mx);
  const float e1 = __expf(mn.y - mx);
  const float e2 = __expf(mn.z - mx);
  const float e3 = __expf(mn.w - mx);
  float s = (e0 + e1) + (e2 + e3);
  s += __shfl_xor(s, 16);
  s += __shfl_xor(s, 32);
  const float inv = 1.f / s;

  // Store: out[b][oc = g*4+r][h][w0+q15]; 16 consecutive pixels per (g,r).
  float* ob = out + (((size_t)(b * OCC + g * 4) * HOUT + h) * WOUT) + w0 + q15;
  const size_t os = (size_t)HOUT * WOUT;
  ob[0 * os] = e0 * inv;
  ob[1 * os] = e1 * inv;
  ob[2 * os] = e2 * inv;
  ob[3 * os] = e3 * inv;
}

extern "C" void kernel_launch(void* const* d_in, const int* in_sizes, int n_in,
                              void* d_out, int out_size, void* d_ws, size_t ws_size,
                              hipStream_t stream) {
  const float* x = (const float*)d_in[0];
  const float* wt = (const float*)d_in[1];
  float* out = (float*)d_out;

  dim3 grid(BB, HOUT, 2);   // b (XCD-pinned), h, w-tile-pair
  dim3 block(256, 1, 1);    // 4 waves = 4 w-tiles
  conv_min_softmax_mfma<<<grid, block, 0, stream>>>(x, wt, out);
}